// Round 2
// baseline (4060.094 us; speedup 1.0000x reference)
//
#include <hip/hip_runtime.h>
#include <hip/hip_bf16.h>

#define Bsz   1024
#define Lseq  50
#define Din   4
#define Hd    512
#define Tlen  30

typedef __hip_bfloat16 bf16;
typedef short s16x8 __attribute__((ext_vector_type(8)));
typedef float f32x4 __attribute__((ext_vector_type(4)));

__device__ __forceinline__ float bf2f(bf16 x){ return __bfloat162float(x); }
__device__ __forceinline__ bf16  f2bf(float x){ return __float2bfloat16(x); }
__device__ __forceinline__ float bfbits2f(short u){
    union { unsigned int ui; float f; } v;
    v.ui = ((unsigned int)(unsigned short)u) << 16;
    return v.f;
}
__device__ __forceinline__ short f2bfbits(float x){
    bf16 h = f2bf(x); short s; __builtin_memcpy(&s, &h, 2); return s;
}
__device__ __forceinline__ float sigm(float x){ return 1.0f/(1.0f + __expf(-x)); }

// ---------------- ws layout (bytes) ----------------
#define OFF_ABUF0   (0u)
#define OFF_ABUF1   (2u<<20)
#define OFF_CBUF    (4u<<20)
#define OFF_HF32    (6u<<20)
#define OFF_ATTNAP  (8u<<20)
#define OFF_XDEC    (9u<<20)
#define OFF_FLAG    ((9u<<20) + (16u<<10))
#define OFF_COMBWR  ((9u<<20) + (32u<<10))
#define OFF_WCACHE  (10u<<20)
#define OFF_ENCOUT  (18u<<20)

// wcache element offsets (bf16 elements), 8-elem aligned per array
#define WC_INPUT 0
#define WC_EWIH  204800
#define WC_EWHH  212992
#define WC_EBIH  1261568
#define WC_EBHH  1263616
#define WC_AW    1265664
#define WC_AB    1291464
#define WC_CW    1291520
#define WC_CB    1555712
#define WC_DWIH  1556224
#define WC_DWHH  2604800
#define WC_DBIH  3653376
#define WC_DBHH  3655424
#define WC_OW    3657472
#define WC_OB    3659520
#define WC_TOTAL 3659524

__device__ __constant__ int WOFF[15] = {
    WC_INPUT, WC_EWIH, WC_EWHH, WC_EBIH, WC_EBHH, WC_AW, WC_AB, WC_CW,
    WC_CB, WC_DWIH, WC_DWHH, WC_DBIH, WC_DBHH, WC_OW, WC_OB };
__device__ __constant__ int WNUM[15] = {
    204800, 8192, 1048576, 2048, 2048, 25800, 50, 264192,
    512, 1048576, 1048576, 2048, 2048, 2048, 4 };

struct Ptrs15 { const void* p[15]; };

// ---------------------------------------------------------------------------
// Dtype probe: bf16 data -> low half-word exponent field never >=0x80
// (|x|>=2 impossible for 0.05*N(0,1)); fp32 data -> those bits are mantissa,
// uniform, ~50% >= 0x80. flag=1 means inputs are fp32.
// ---------------------------------------------------------------------------
__global__ void probe_kernel(const unsigned int* __restrict__ w, int* flag){
    __shared__ int cnt;
    if (threadIdx.x == 0) cnt = 0;
    __syncthreads();
    int c = 0;
    for (int i = threadIdx.x; i < 4096; i += 256){
        unsigned e = (w[i] >> 7) & 0xFFu;
        c += (e >= 0x80u) ? 1 : 0;
    }
    atomicAdd(&cnt, c);
    __syncthreads();
    if (threadIdx.x == 0) *flag = (cnt > 400) ? 1 : 0;
}

// Normalize all float inputs into a contiguous bf16 cache.
__global__ __launch_bounds__(256) void convert_kernel(
    Ptrs15 srcs, const int* __restrict__ flag, bf16* __restrict__ dst)
{
    const int f = *flag;
    for (int idx = blockIdx.x*256 + threadIdx.x; idx < WC_TOTAL;
         idx += gridDim.x*256){
        int a = 0;
#pragma unroll
        for (int j = 1; j < 15; ++j) if (idx >= WOFF[j]) a = j;
        const int local = idx - WOFF[a];
        if (local >= WNUM[a]) continue;
        bf16 v;
        if (f) v = f2bf(((const float*)srcs.p[a])[local]);
        else   v = ((const bf16*)srcs.p[a])[local];
        dst[idx] = v;
    }
}

// zero h columns of both A-buffers, zero c, repack comb_W[:,4:] -> 512x512
__global__ __launch_bounds__(256) void setup_kernel(
    bf16* __restrict__ Abuf0, bf16* __restrict__ Abuf1,
    float* __restrict__ cbuf, bf16* __restrict__ combWr,
    const bf16* __restrict__ cWc)
{
    const unsigned idx = blockIdx.x*256u + threadIdx.x;
    if (idx < (unsigned)Bsz*Hd){
        const unsigned row = idx >> 9, col = idx & (Hd-1);
        const bf16 z = f2bf(0.0f);
        Abuf0[(size_t)row*1024 + Hd + col] = z;
        Abuf1[(size_t)row*1024 + Hd + col] = z;
        cbuf[idx] = 0.0f;
    }
    if (idx < (unsigned)Hd*Hd)
        combWr[idx] = cWc[(size_t)(idx >> 9)*(Hd+Din) + Din + (idx & (Hd-1))];
}

// ---------------------------------------------------------------------------
// Fused gates GEMM + LSTM elementwise. Reads A (h or comb|h) from Ain,
// writes new h into Aout (different buffer -> no race).
// N-mapping: n -> gate = n&3, hcol = hc0 + (n>>2); 4 gates of one (b,hcol)
// sit in 4 adjacent lanes of the MFMA D-frag. Grid 256 WGs, 256 thr.
// ---------------------------------------------------------------------------
__global__ __launch_bounds__(256) void gates_kernel(
    const bf16* __restrict__ A, int lda, int K,
    const bf16* __restrict__ W1, const bf16* __restrict__ W2,
    const bf16* __restrict__ bih, const bf16* __restrict__ bhh,
    const bf16* __restrict__ Wx,                // [2048 x 4] or nullptr
    const bf16* __restrict__ xsrc, int ldx,
    float* __restrict__ cbuf,
    bf16* __restrict__ hout, int ldh,           // new-h buffer (bf16)
    bf16* __restrict__ hout2, int ldh2,         // optional enc_out slice
    float* __restrict__ hf32)
{
    const int wg = blockIdx.x;
    const int mt = wg >> 4, nt = wg & 15;
    const int bm0 = mt << 6;
    const int hc0 = nt << 5;
    const int tid = threadIdx.x;
    const int wave = tid >> 6, lane = tid & 63;
    const int wm = wave >> 1, wn = wave & 1;
    const int quad = lane >> 4, l15 = lane & 15;

    int arow[2], ng[4];
#pragma unroll
    for (int am = 0; am < 2; ++am) arow[am] = bm0 + wm*32 + am*16 + l15;
#pragma unroll
    for (int an = 0; an < 4; ++an){
        int n = wn*64 + an*16 + l15;
        ng[an] = (n & 3)*Hd + hc0 + (n >> 2);
    }

    f32x4 acc[2][4];
#pragma unroll
    for (int am=0; am<2; ++am)
#pragma unroll
      for (int an=0; an<4; ++an) acc[am][an] = (f32x4)0.0f;

    for (int k0 = 0; k0 < K; k0 += 32){
        const bf16* Wb = (k0 < Hd) ? W1 : W2;
        const int kk = (k0 & (Hd-1)) + quad*8;
        s16x8 bfrag[4];
#pragma unroll
        for (int an=0; an<4; ++an)
            bfrag[an] = *reinterpret_cast<const s16x8*>(Wb + (size_t)ng[an]*Hd + kk);
        s16x8 afrag[2];
        const int ka = k0 + quad*8;
#pragma unroll
        for (int am=0; am<2; ++am)
            afrag[am] = *reinterpret_cast<const s16x8*>(A + (size_t)arow[am]*lda + ka);
#pragma unroll
        for (int am=0; am<2; ++am)
#pragma unroll
          for (int an=0; an<4; ++an)
            acc[am][an] = __builtin_amdgcn_mfma_f32_16x16x32_bf16(
                afrag[am], bfrag[an], acc[am][an], 0, 0, 0);
    }

    const int lbase = lane & ~3;
#pragma unroll
    for (int am=0; am<2; ++am){
#pragma unroll
      for (int an=0; an<4; ++an){
        const int n = wn*64 + an*16 + l15;
        const int g = ng[an];
        const float bias = bf2f(bih[g]) + bf2f(bhh[g]);
#pragma unroll
        for (int r=0; r<4; ++r){
            const int m = bm0 + wm*32 + am*16 + quad*4 + r;
            float gv = acc[am][an][r] + bias;
            if (Wx){
                const bf16* xp = xsrc + (size_t)m*ldx;
#pragma unroll
                for (int d=0; d<Din; ++d) gv += bf2f(xp[d]) * bf2f(Wx[g*Din + d]);
            }
            float gi = __shfl(gv, lbase+0);
            float gf = __shfl(gv, lbase+1);
            float gg = __shfl(gv, lbase+2);
            float go = __shfl(gv, lbase+3);
            if ((lane & 3) == 0){
                const int hcol = hc0 + (n >> 2);
                const size_t ci = (size_t)m*Hd + hcol;
                const float cn = sigm(gf)*cbuf[ci] + sigm(gi)*tanhf(gg);
                cbuf[ci] = cn;
                const float hv = sigm(go)*tanhf(cn);
                const bf16 hb = f2bf(hv);
                hout[(size_t)m*ldh + hcol] = hb;
                hf32[ci] = hv;
                if (hout2) hout2[(size_t)m*ldh2 + hcol] = hb;
            }
        }
      }
    }
}

// ---------------------------------------------------------------------------
// comb = relu([x, attn_applied] @ comb_W.T + comb_b). Grid 64 WGs.
// ---------------------------------------------------------------------------
__global__ __launch_bounds__(256) void comb_kernel(
    const bf16* __restrict__ A,      // attn_applied [B x 512]
    const bf16* __restrict__ Wr,     // repacked comb_W[:,4:] [512 x 512]
    const bf16* __restrict__ combW,  // cached original [512 x 516]
    const bf16* __restrict__ combB,
    const bf16* __restrict__ xdec,
    bf16* __restrict__ out)          // A-buffer, ld 1024, cols 0..511
{
    const int wg = blockIdx.x;
    const int mt = wg >> 2, nt = wg & 3;
    const int bm0 = mt << 6, n0 = nt << 7;
    const int tid = threadIdx.x;
    const int wave = tid >> 6, lane = tid & 63;
    const int wm = wave >> 1, wn = wave & 1;
    const int quad = lane >> 4, l15 = lane & 15;

    int arow[2], ncol[4];
#pragma unroll
    for (int am=0; am<2; ++am) arow[am] = bm0 + wm*32 + am*16 + l15;
#pragma unroll
    for (int an=0; an<4; ++an) ncol[an] = n0 + wn*64 + an*16 + l15;

    f32x4 acc[2][4];
#pragma unroll
    for (int am=0; am<2; ++am)
#pragma unroll
      for (int an=0; an<4; ++an) acc[am][an] = (f32x4)0.0f;

    for (int k0 = 0; k0 < Hd; k0 += 32){
        const int kk = k0 + quad*8;
        s16x8 bfrag[4];
#pragma unroll
        for (int an=0; an<4; ++an)
            bfrag[an] = *reinterpret_cast<const s16x8*>(Wr + (size_t)ncol[an]*Hd + kk);
        s16x8 afrag[2];
#pragma unroll
        for (int am=0; am<2; ++am)
            afrag[am] = *reinterpret_cast<const s16x8*>(A + (size_t)arow[am]*Hd + kk);
#pragma unroll
        for (int am=0; am<2; ++am)
#pragma unroll
          for (int an=0; an<4; ++an)
            acc[am][an] = __builtin_amdgcn_mfma_f32_16x16x32_bf16(
                afrag[am], bfrag[an], acc[am][an], 0, 0, 0);
    }

#pragma unroll
    for (int am=0; am<2; ++am){
#pragma unroll
      for (int an=0; an<4; ++an){
        const int n = ncol[an];
        const float bias = bf2f(combB[n]);
#pragma unroll
        for (int r=0; r<4; ++r){
            const int m = bm0 + wm*32 + am*16 + quad*4 + r;
            float v = acc[am][an][r] + bias;
            const bf16* xp = xdec + (size_t)m*Din;
#pragma unroll
            for (int d=0; d<Din; ++d) v += bf2f(xp[d]) * bf2f(combW[(size_t)n*(Hd+Din) + d]);
            v = fmaxf(v, 0.0f);
            out[(size_t)m*1024 + n] = f2bf(v);
        }
      }
    }
}

// ---------------------------------------------------------------------------
// Per decoder step: pred(t-1) (t>0) + attention + context. One wave per row.
// h_r[b,j] = h[2j + b/512, b%512] (flat reshape, not transpose).
// ---------------------------------------------------------------------------
__global__ __launch_bounds__(256) void attn_kernel(
    int t, const int* __restrict__ flagp,
    const bf16* __restrict__ input,
    const float* __restrict__ hf32,
    const bf16* __restrict__ enc_out,
    const bf16* __restrict__ attnW, const bf16* __restrict__ attnB,
    const bf16* __restrict__ outW,  const bf16* __restrict__ outB,
    void* __restrict__ dout,
    bf16* __restrict__ xdec,
    bf16* __restrict__ attnap)
{
    __shared__ float hr_s[4][Hd];
    const int f32out = *flagp;
    const int wave = threadIdx.x >> 6, lane = threadIdx.x & 63;
    const int b = blockIdx.x*4 + wave;

    float x0, x1, x2, x3;
    if (t == 0){
        const bf16* xp = input + ((size_t)b*Lseq + (Lseq-1))*Din;
        x0 = bf2f(xp[0]); x1 = bf2f(xp[1]); x2 = bf2f(xp[2]); x3 = bf2f(xp[3]);
    } else {
        float p0=0.f, p1=0.f, p2=0.f, p3=0.f;
        const float* hb = hf32 + (size_t)b*Hd;
        for (int k=lane; k<Hd; k+=64){
            const float hv = hb[k];
            p0 += hv*bf2f(outW[0*Hd+k]);
            p1 += hv*bf2f(outW[1*Hd+k]);
            p2 += hv*bf2f(outW[2*Hd+k]);
            p3 += hv*bf2f(outW[3*Hd+k]);
        }
#pragma unroll
        for (int off=32; off; off>>=1){
            p0 += __shfl_down(p0, off); p1 += __shfl_down(p1, off);
            p2 += __shfl_down(p2, off); p3 += __shfl_down(p3, off);
        }
        x0 = __shfl(p0,0) + bf2f(outB[0]);
        x1 = __shfl(p1,0) + bf2f(outB[1]);
        x2 = __shfl(p2,0) + bf2f(outB[2]);
        x3 = __shfl(p3,0) + bf2f(outB[3]);
        if (lane == 0){
            const size_t o = ((size_t)b*Tlen + (t-1))*Din;
            if (f32out){
                float* dp = (float*)dout + o;
                dp[0]=x0; dp[1]=x1; dp[2]=x2; dp[3]=x3;
            } else {
                bf16* dp = (bf16*)dout + o;
                dp[0]=f2bf(x0); dp[1]=f2bf(x1); dp[2]=f2bf(x2); dp[3]=f2bf(x3);
            }
        }
    }
    if (lane == 0){
        bf16* xp = xdec + (size_t)b*Din;
        xp[0]=f2bf(x0); xp[1]=f2bf(x1); xp[2]=f2bf(x2); xp[3]=f2bf(x3);
    }

    const int s = b >> 9, p = b & (Hd-1);
    for (int j=lane; j<Hd; j+=64)
        hr_s[wave][j] = hf32[(size_t)(2*j + s)*Hd + p];
    __syncthreads();

    float logit = -3.0e38f;
    if (lane < Lseq){
        const bf16* wr = attnW + (size_t)lane*(Hd+Din);
        float a = bf2f(attnB[lane]);
        a += x0*bf2f(wr[0]) + x1*bf2f(wr[1]) + x2*bf2f(wr[2]) + x3*bf2f(wr[3]);
        for (int j=0; j<Hd; ++j) a += hr_s[wave][j]*bf2f(wr[4+j]);
        logit = a;
    }
    float mx = logit;
#pragma unroll
    for (int off=32; off; off>>=1) mx = fmaxf(mx, __shfl_xor(mx, off));
    const float e = (lane < Lseq) ? __expf(logit - mx) : 0.0f;
    float se = e;
#pragma unroll
    for (int off=32; off; off>>=1) se += __shfl_xor(se, off);
    const float myaw = e / se;

    float acc8[8] = {0.f,0.f,0.f,0.f,0.f,0.f,0.f,0.f};
    const bf16* eb = enc_out + (size_t)b*Lseq*Hd + lane*8;
    for (int l=0; l<Lseq; ++l){
        const float w = __shfl(myaw, l);
        const s16x8 ch = *reinterpret_cast<const s16x8*>(eb + (size_t)l*Hd);
#pragma unroll
        for (int q=0; q<8; ++q) acc8[q] += w * bfbits2f(ch[q]);
    }
    s16x8 ov;
#pragma unroll
    for (int q=0; q<8; ++q) ov[q] = f2bfbits(acc8[q]);
    *reinterpret_cast<s16x8*>(attnap + (size_t)b*Hd + lane*8) = ov;
}

// final pred (t = T-1)
__global__ __launch_bounds__(256) void pred_kernel(
    const int* __restrict__ flagp,
    const float* __restrict__ hf32,
    const bf16* __restrict__ outW, const bf16* __restrict__ outB,
    void* __restrict__ dout)
{
    const int f32out = *flagp;
    const int wave = threadIdx.x >> 6, lane = threadIdx.x & 63;
    const int b = blockIdx.x*4 + wave;
    float p0=0.f, p1=0.f, p2=0.f, p3=0.f;
    const float* hb = hf32 + (size_t)b*Hd;
    for (int k=lane; k<Hd; k+=64){
        const float hv = hb[k];
        p0 += hv*bf2f(outW[0*Hd+k]);
        p1 += hv*bf2f(outW[1*Hd+k]);
        p2 += hv*bf2f(outW[2*Hd+k]);
        p3 += hv*bf2f(outW[3*Hd+k]);
    }
#pragma unroll
    for (int off=32; off; off>>=1){
        p0 += __shfl_down(p0, off); p1 += __shfl_down(p1, off);
        p2 += __shfl_down(p2, off); p3 += __shfl_down(p3, off);
    }
    if (lane == 0){
        const size_t o = ((size_t)b*Tlen + (Tlen-1))*Din;
        const float r0 = p0 + bf2f(outB[0]), r1 = p1 + bf2f(outB[1]);
        const float r2 = p2 + bf2f(outB[2]), r3 = p3 + bf2f(outB[3]);
        if (f32out){
            float* dp = (float*)dout + o;
            dp[0]=r0; dp[1]=r1; dp[2]=r2; dp[3]=r3;
        } else {
            bf16* dp = (bf16*)dout + o;
            dp[0]=f2bf(r0); dp[1]=f2bf(r1); dp[2]=f2bf(r2); dp[3]=f2bf(r3);
        }
    }
}

extern "C" void kernel_launch(void* const* d_in, const int* in_sizes, int n_in,
                              void* d_out, int out_size, void* d_ws, size_t ws_size,
                              hipStream_t stream)
{
    char* ws = (char*)d_ws;
    bf16*  Abuf0   = (bf16*)(ws + OFF_ABUF0);
    bf16*  Abuf1   = (bf16*)(ws + OFF_ABUF1);
    float* cbuf    = (float*)(ws + OFF_CBUF);
    float* hf32    = (float*)(ws + OFF_HF32);
    bf16*  attnap  = (bf16*)(ws + OFF_ATTNAP);
    bf16*  xdec    = (bf16*)(ws + OFF_XDEC);
    int*   flag    = (int*)(ws + OFF_FLAG);
    bf16*  combWr  = (bf16*)(ws + OFF_COMBWR);
    bf16*  wc      = (bf16*)(ws + OFF_WCACHE);
    bf16*  enc_out = (bf16*)(ws + OFF_ENCOUT);

    const bf16 *c_input = wc+WC_INPUT, *c_eWih = wc+WC_EWIH, *c_eWhh = wc+WC_EWHH,
               *c_ebih = wc+WC_EBIH, *c_ebhh = wc+WC_EBHH, *c_aW = wc+WC_AW,
               *c_ab = wc+WC_AB, *c_cW = wc+WC_CW, *c_cb = wc+WC_CB,
               *c_dWih = wc+WC_DWIH, *c_dWhh = wc+WC_DWHH, *c_dbih = wc+WC_DBIH,
               *c_dbhh = wc+WC_DBHH, *c_oW = wc+WC_OW, *c_ob = wc+WC_OB;

    bf16* Abuf[2] = {Abuf0, Abuf1};

    probe_kernel<<<1, 256, 0, stream>>>((const unsigned int*)d_in[3], flag);

    Ptrs15 srcs;
    srcs.p[0]=d_in[0];  srcs.p[1]=d_in[2];  srcs.p[2]=d_in[3];  srcs.p[3]=d_in[4];
    srcs.p[4]=d_in[5];  srcs.p[5]=d_in[6];  srcs.p[6]=d_in[7];  srcs.p[7]=d_in[8];
    srcs.p[8]=d_in[9];  srcs.p[9]=d_in[10]; srcs.p[10]=d_in[11];srcs.p[11]=d_in[12];
    srcs.p[12]=d_in[13];srcs.p[13]=d_in[14];srcs.p[14]=d_in[15];
    convert_kernel<<<1024, 256, 0, stream>>>(srcs, flag, wc);

    setup_kernel<<<2048, 256, 0, stream>>>(Abuf0, Abuf1, cbuf, combWr, c_cW);

    // encoder: 50 fused LSTM steps, h double-buffered
    for (int t = 0; t < Lseq; ++t){
        gates_kernel<<<256, 256, 0, stream>>>(
            Abuf[t&1] + Hd, 1024, Hd,
            c_eWhh, c_eWhh, c_ebih, c_ebhh,
            c_eWih, c_input + (size_t)t*Din, Lseq*Din,
            cbuf,
            Abuf[(t+1)&1] + Hd, 1024,
            enc_out + (size_t)t*Hd, Lseq*Hd,
            hf32);
    }
    // after 50 steps h_enc is in Abuf[0] cols 512..1023

    // decoder: 30 steps
    for (int t = 0; t < Tlen; ++t){
        const int p = t & 1;
        attn_kernel<<<256, 256, 0, stream>>>(
            t, flag, c_input, hf32, enc_out, c_aW, c_ab, c_oW, c_ob,
            d_out, xdec, attnap);
        comb_kernel<<<64, 256, 0, stream>>>(
            attnap, combWr, c_cW, c_cb, xdec, Abuf[p]);
        gates_kernel<<<256, 256, 0, stream>>>(
            Abuf[p], 1024, 1024,
            c_dWih, c_dWhh, c_dbih, c_dbhh,
            nullptr, nullptr, 0,
            cbuf,
            Abuf[(t+1)&1] + Hd, 1024,
            nullptr, 0,
            hf32);
    }

    pred_kernel<<<256, 256, 0, stream>>>(flag, hf32, c_oW, c_ob, d_out);
}

// Round 3
// 3630.751 us; speedup vs baseline: 1.1183x; 1.1183x over previous
//
#include <hip/hip_runtime.h>
#include <hip/hip_bf16.h>

#define Bsz   1024
#define Lseq  50
#define Din   4
#define Hd    512
#define Tlen  30

typedef __hip_bfloat16 bf16;
typedef short s16x8 __attribute__((ext_vector_type(8)));
typedef short s16x4 __attribute__((ext_vector_type(4)));
typedef float f32x4 __attribute__((ext_vector_type(4)));

__device__ __forceinline__ float bf2f(bf16 x){ return __bfloat162float(x); }
__device__ __forceinline__ bf16  f2bf(float x){ return __float2bfloat16(x); }
__device__ __forceinline__ float bfbits2f(short u){
    union { unsigned int ui; float f; } v;
    v.ui = ((unsigned int)(unsigned short)u) << 16;
    return v.f;
}
__device__ __forceinline__ short f2bfbits(float x){
    bf16 h = f2bf(x); short s; __builtin_memcpy(&s, &h, 2); return s;
}
__device__ __forceinline__ float sigm(float x){ return 1.0f/(1.0f + __expf(-x)); }

// ---------------- ws layout (bytes) ----------------
#define OFF_ABUF0   (0u)
#define OFF_ABUF1   (2u<<20)
#define OFF_CBUF    (4u<<20)
#define OFF_HF32    (6u<<20)
#define OFF_ATTNAP  (8u<<20)
#define OFF_XDEC    (9u<<20)
#define OFF_FLAG    ((9u<<20) + (16u<<10))
#define OFF_COMBWR  ((9u<<20) + (32u<<10))
#define OFF_ATTNWR  ((9u<<20) + (600u<<10))
#define OFF_WCACHE  (10u<<20)
#define OFF_ENCOUT  (18u<<20)

// wcache element offsets (bf16 elements), 8-elem aligned per array
#define WC_INPUT 0
#define WC_EWIH  204800
#define WC_EWHH  212992
#define WC_EBIH  1261568
#define WC_EBHH  1263616
#define WC_AW    1265664
#define WC_AB    1291464
#define WC_CW    1291520
#define WC_CB    1555712
#define WC_DWIH  1556224
#define WC_DWHH  2604800
#define WC_DBIH  3653376
#define WC_DBHH  3655424
#define WC_OW    3657472
#define WC_OB    3659520
#define WC_TOTAL 3659524

__device__ __constant__ int WOFF[15] = {
    WC_INPUT, WC_EWIH, WC_EWHH, WC_EBIH, WC_EBHH, WC_AW, WC_AB, WC_CW,
    WC_CB, WC_DWIH, WC_DWHH, WC_DBIH, WC_DBHH, WC_OW, WC_OB };
__device__ __constant__ int WNUM[15] = {
    204800, 8192, 1048576, 2048, 2048, 25800, 50, 264192,
    512, 1048576, 1048576, 2048, 2048, 2048, 4 };

struct Ptrs15 { const void* p[15]; };

// ---------------------------------------------------------------------------
// Dtype probe: bf16 data -> low half-word "exponent" bits never >=0x80 for
// 0.05*N(0,1); fp32 data -> those bits are mid-mantissa, ~50% >= 0x80.
// flag=1 means inputs are fp32.
// ---------------------------------------------------------------------------
__global__ void probe_kernel(const unsigned int* __restrict__ w, int* flag){
    __shared__ int cnt;
    if (threadIdx.x == 0) cnt = 0;
    __syncthreads();
    int c = 0;
    for (int i = threadIdx.x; i < 4096; i += 256){
        unsigned e = (w[i] >> 7) & 0xFFu;
        c += (e >= 0x80u) ? 1 : 0;
    }
    atomicAdd(&cnt, c);
    __syncthreads();
    if (threadIdx.x == 0) *flag = (cnt > 400) ? 1 : 0;
}

// Normalize all float inputs into a contiguous bf16 cache.
__global__ __launch_bounds__(256) void convert_kernel(
    Ptrs15 srcs, const int* __restrict__ flag, bf16* __restrict__ dst)
{
    const int f = *flag;
    for (int idx = blockIdx.x*256 + threadIdx.x; idx < WC_TOTAL;
         idx += gridDim.x*256){
        int a = 0;
#pragma unroll
        for (int j = 1; j < 15; ++j) if (idx >= WOFF[j]) a = j;
        const int local = idx - WOFF[a];
        if (local >= WNUM[a]) continue;
        bf16 v;
        if (f) v = f2bf(((const float*)srcs.p[a])[local]);
        else   v = ((const bf16*)srcs.p[a])[local];
        dst[idx] = v;
    }
}

// zero h cols of both A-buffers, zero c, repack comb_W[:,4:] and attn_W[:,4:]
__global__ __launch_bounds__(256) void setup_kernel(
    bf16* __restrict__ Abuf0, bf16* __restrict__ Abuf1,
    float* __restrict__ cbuf, bf16* __restrict__ combWr,
    bf16* __restrict__ attnWr,
    const bf16* __restrict__ cWc, const bf16* __restrict__ aWc)
{
    const unsigned idx = blockIdx.x*256u + threadIdx.x;
    if (idx < (unsigned)Bsz*Hd){
        const unsigned row = idx >> 9, col = idx & (Hd-1);
        const bf16 z = f2bf(0.0f);
        Abuf0[(size_t)row*1024 + Hd + col] = z;
        Abuf1[(size_t)row*1024 + Hd + col] = z;
        cbuf[idx] = 0.0f;
    }
    if (idx < (unsigned)Hd*Hd)
        combWr[idx] = cWc[(size_t)(idx >> 9)*(Hd+Din) + Din + (idx & (Hd-1))];
    if (idx < (unsigned)Lseq*Hd)
        attnWr[idx] = aWc[(size_t)(idx >> 9)*(Hd+Din) + Din + (idx & (Hd-1))];
}

// ---------------------------------------------------------------------------
// Fused gates GEMM + LSTM elementwise. Grid 256 WGs x 512 thr (8 waves).
// Tile 64m x 128n; wave = 1 m-frag x 4 n-frags (16x64), 4 MFMAs/iter.
// TWO: K=1024 as two statically-unrolled 512-halves (W1 then W2).
// N-map: n -> gate = n&3, hcol = hc0 + (n>>2).
// ---------------------------------------------------------------------------
template<bool TWO, bool HASX, bool WENC>
__global__ __launch_bounds__(512, 2) void gates_kernel(
    const bf16* __restrict__ A, int lda,
    const bf16* __restrict__ W1, const bf16* __restrict__ W2,
    const bf16* __restrict__ bih, const bf16* __restrict__ bhh,
    const bf16* __restrict__ Wx,                // [2048 x 4] (HASX)
    const bf16* __restrict__ xsrc, int ldx,     // x row m at xsrc + m*ldx
    float* __restrict__ cbuf,
    bf16* __restrict__ hout,                    // new-h, ld 1024
    bf16* __restrict__ hout2, int ldh2,         // optional enc_out slice
    float* __restrict__ hf32)
{
    const int wg = blockIdx.x;
    const int mt = wg >> 4, nt = wg & 15;
    const int bm0 = mt << 6, hc0 = nt << 5;
    const int tid = threadIdx.x;
    const int wave = tid >> 6, lane = tid & 63;
    const int wm = wave >> 1, wn = wave & 1;
    const int quad = lane >> 4, l15 = lane & 15;

    const int arow = bm0 + wm*16 + l15;
    int ng[4];
#pragma unroll
    for (int an = 0; an < 4; ++an){
        const int n = wn*64 + an*16 + l15;
        ng[an] = (n & 3)*Hd + hc0 + (n >> 2);
    }

    // hoisted epilogue operands
    float bias[4];
#pragma unroll
    for (int an = 0; an < 4; ++an)
        bias[an] = bf2f(bih[ng[an]]) + bf2f(bhh[ng[an]]);
    float xv[4][4], wxv[4][4];
    if (HASX){
#pragma unroll
        for (int r = 0; r < 4; ++r){
            const int m = bm0 + wm*16 + quad*4 + r;
            const s16x4 t = *reinterpret_cast<const s16x4*>(xsrc + (size_t)m*ldx);
#pragma unroll
            for (int d = 0; d < 4; ++d) xv[r][d] = bfbits2f(t[d]);
        }
#pragma unroll
        for (int an = 0; an < 4; ++an){
            const s16x4 t = *reinterpret_cast<const s16x4*>(Wx + (size_t)ng[an]*Din);
#pragma unroll
            for (int d = 0; d < 4; ++d) wxv[an][d] = bfbits2f(t[d]);
        }
    }

    f32x4 acc[4];
#pragma unroll
    for (int an = 0; an < 4; ++an) acc[an] = (f32x4)0.0f;

    const bf16* Ab = A + (size_t)arow*lda + quad*8;
    const bf16* wbase[2] = { W1, W2 };
#pragma unroll
    for (int h = 0; h < (TWO ? 2 : 1); ++h){
        const bf16* Wb = wbase[h];
        const bf16* Ah = Ab + h*Hd;
#pragma unroll
        for (int kk = 0; kk < 16; ++kk){
            const int k = kk*32 + quad*8;
            s16x8 bfr[4];
#pragma unroll
            for (int an = 0; an < 4; ++an)
                bfr[an] = *reinterpret_cast<const s16x8*>(Wb + (size_t)ng[an]*Hd + k);
            const s16x8 afr = *reinterpret_cast<const s16x8*>(Ah + kk*32);
#pragma unroll
            for (int an = 0; an < 4; ++an)
                acc[an] = __builtin_amdgcn_mfma_f32_16x16x32_bf16(afr, bfr[an], acc[an], 0, 0, 0);
        }
    }

    const int lbase = lane & ~3;
#pragma unroll
    for (int an = 0; an < 4; ++an){
        const int n = wn*64 + an*16 + l15;
        const int hcol = hc0 + (n >> 2);
#pragma unroll
        for (int r = 0; r < 4; ++r){
            const int m = bm0 + wm*16 + quad*4 + r;
            float gv = acc[an][r] + bias[an];
            if (HASX)
                gv += xv[r][0]*wxv[an][0] + xv[r][1]*wxv[an][1]
                    + xv[r][2]*wxv[an][2] + xv[r][3]*wxv[an][3];
            const float gi = __shfl(gv, lbase+0);
            const float gf = __shfl(gv, lbase+1);
            const float gg = __shfl(gv, lbase+2);
            const float go = __shfl(gv, lbase+3);
            if ((lane & 3) == 0){
                const size_t ci = (size_t)m*Hd + hcol;
                const float cn = sigm(gf)*cbuf[ci] + sigm(gi)*tanhf(gg);
                cbuf[ci] = cn;
                const float hv = sigm(go)*tanhf(cn);
                const bf16 hb = f2bf(hv);
                hout[(size_t)m*1024 + hcol] = hb;
                hf32[ci] = hv;
                if (WENC) hout2[(size_t)m*ldh2 + hcol] = hb;
            }
        }
    }
}

// ---------------------------------------------------------------------------
// comb = relu([x, attn_applied] @ comb_W.T + comb_b).
// Grid 256 WGs (32 mt x 8 nt), tile 32m x 64n, 256 thr; wave = 16x32.
// ---------------------------------------------------------------------------
__global__ __launch_bounds__(256) void comb_kernel(
    const bf16* __restrict__ A,      // attn_applied [B x 512]
    const bf16* __restrict__ Wr,     // repacked comb_W[:,4:] [512 x 512]
    const bf16* __restrict__ combW,  // original [512 x 516] (x cols)
    const bf16* __restrict__ combB,
    const bf16* __restrict__ xdec,
    bf16* __restrict__ out)          // A-buffer, ld 1024, cols 0..511
{
    const int wg = blockIdx.x;
    const int mt = wg >> 3, nt = wg & 7;
    const int bm0 = mt << 5, n0 = nt << 6;
    const int tid = threadIdx.x;
    const int wave = tid >> 6, lane = tid & 63;
    const int wm = wave >> 1, wn = wave & 1;
    const int quad = lane >> 4, l15 = lane & 15;

    const int arow = bm0 + wm*16 + l15;
    int ncol[2];
#pragma unroll
    for (int j = 0; j < 2; ++j) ncol[j] = n0 + wn*32 + j*16 + l15;

    float bias[2], wxv[2][4];
#pragma unroll
    for (int j = 0; j < 2; ++j){
        bias[j] = bf2f(combB[ncol[j]]);
        const s16x4 t = *reinterpret_cast<const s16x4*>(combW + (size_t)ncol[j]*(Hd+Din));
#pragma unroll
        for (int d = 0; d < 4; ++d) wxv[j][d] = bfbits2f(t[d]);
    }
    float xv[4][4];
#pragma unroll
    for (int r = 0; r < 4; ++r){
        const int m = bm0 + wm*16 + quad*4 + r;
        const s16x4 t = *reinterpret_cast<const s16x4*>(xdec + (size_t)m*Din);
#pragma unroll
        for (int d = 0; d < 4; ++d) xv[r][d] = bfbits2f(t[d]);
    }

    f32x4 acc[2];
#pragma unroll
    for (int j = 0; j < 2; ++j) acc[j] = (f32x4)0.0f;

    const bf16* Ab = A + (size_t)arow*Hd + quad*8;
#pragma unroll
    for (int kk = 0; kk < 16; ++kk){
        const int k = kk*32 + quad*8;
        s16x8 bfr[2];
#pragma unroll
        for (int j = 0; j < 2; ++j)
            bfr[j] = *reinterpret_cast<const s16x8*>(Wr + (size_t)ncol[j]*Hd + k);
        const s16x8 afr = *reinterpret_cast<const s16x8*>(Ab + kk*32);
#pragma unroll
        for (int j = 0; j < 2; ++j)
            acc[j] = __builtin_amdgcn_mfma_f32_16x16x32_bf16(afr, bfr[j], acc[j], 0, 0, 0);
    }

#pragma unroll
    for (int j = 0; j < 2; ++j){
        const int n = ncol[j];
#pragma unroll
        for (int r = 0; r < 4; ++r){
            const int m = bm0 + wm*16 + quad*4 + r;
            float v = acc[j][r] + bias[j]
                    + xv[r][0]*wxv[j][0] + xv[r][1]*wxv[j][1]
                    + xv[r][2]*wxv[j][2] + xv[r][3]*wxv[j][3];
            v = fmaxf(v, 0.0f);
            out[(size_t)m*1024 + n] = f2bf(v);
        }
    }
}

// ---------------------------------------------------------------------------
// Per decoder step: pred(t-1) (t>0) + attention + context. One wave per row.
// h_r[b,j] = h[2j + b/512, b%512] (flat reshape).
// ---------------------------------------------------------------------------
__global__ __launch_bounds__(256) void attn_kernel(
    int t, const int* __restrict__ flagp,
    const bf16* __restrict__ input,
    const float* __restrict__ hf32,
    const bf16* __restrict__ enc_out,
    const bf16* __restrict__ attnW,  // original [50 x 516] (x cols)
    const bf16* __restrict__ attnWr, // repacked [50 x 512]
    const bf16* __restrict__ attnB,
    const bf16* __restrict__ outW,  const bf16* __restrict__ outB,
    void* __restrict__ dout,
    bf16* __restrict__ xdec,
    bf16* __restrict__ attnap)
{
    __shared__ float hr_s[4][Hd];
    const int f32out = *flagp;
    const int wave = threadIdx.x >> 6, lane = threadIdx.x & 63;
    const int b = blockIdx.x*4 + wave;

    float x0, x1, x2, x3;
    if (t == 0){
        const bf16* xp = input + ((size_t)b*Lseq + (Lseq-1))*Din;
        x0 = bf2f(xp[0]); x1 = bf2f(xp[1]); x2 = bf2f(xp[2]); x3 = bf2f(xp[3]);
    } else {
        float p0=0.f, p1=0.f, p2=0.f, p3=0.f;
        const float* hb = hf32 + (size_t)b*Hd;
        for (int k=lane; k<Hd; k+=64){
            const float hv = hb[k];
            p0 += hv*bf2f(outW[0*Hd+k]);
            p1 += hv*bf2f(outW[1*Hd+k]);
            p2 += hv*bf2f(outW[2*Hd+k]);
            p3 += hv*bf2f(outW[3*Hd+k]);
        }
#pragma unroll
        for (int off=32; off; off>>=1){
            p0 += __shfl_down(p0, off); p1 += __shfl_down(p1, off);
            p2 += __shfl_down(p2, off); p3 += __shfl_down(p3, off);
        }
        x0 = __shfl(p0,0) + bf2f(outB[0]);
        x1 = __shfl(p1,0) + bf2f(outB[1]);
        x2 = __shfl(p2,0) + bf2f(outB[2]);
        x3 = __shfl(p3,0) + bf2f(outB[3]);
        if (lane == 0){
            const size_t o = ((size_t)b*Tlen + (t-1))*Din;
            if (f32out){
                float* dp = (float*)dout + o;
                dp[0]=x0; dp[1]=x1; dp[2]=x2; dp[3]=x3;
            } else {
                bf16* dp = (bf16*)dout + o;
                dp[0]=f2bf(x0); dp[1]=f2bf(x1); dp[2]=f2bf(x2); dp[3]=f2bf(x3);
            }
        }
    }
    if (lane == 0){
        bf16* xp = xdec + (size_t)b*Din;
        xp[0]=f2bf(x0); xp[1]=f2bf(x1); xp[2]=f2bf(x2); xp[3]=f2bf(x3);
    }

    const int s = b >> 9, p = b & (Hd-1);
    for (int j=lane; j<Hd; j+=64)
        hr_s[wave][j] = hf32[(size_t)(2*j + s)*Hd + p];
    __syncthreads();

    float logit = -3.0e38f;
    if (lane < Lseq){
        float a0 = bf2f(attnB[lane]);
        {
            const bf16* wx = attnW + (size_t)lane*(Hd+Din);
            a0 += x0*bf2f(wx[0]) + x1*bf2f(wx[1]) + x2*bf2f(wx[2]) + x3*bf2f(wx[3]);
        }
        float a1 = 0.f, a2 = 0.f, a3 = 0.f;
        const bf16* wr = attnWr + (size_t)lane*Hd;
        for (int j = 0; j < Hd; j += 16){
            float acc4[4] = {0.f,0.f,0.f,0.f};
#pragma unroll
            for (int q = 0; q < 4; ++q){
                const float4 hv = *reinterpret_cast<const float4*>(&hr_s[wave][j + q*4]);
                const s16x4 wv = *reinterpret_cast<const s16x4*>(wr + j + q*4);
                acc4[q] = hv.x*bfbits2f(wv[0]) + hv.y*bfbits2f(wv[1])
                        + hv.z*bfbits2f(wv[2]) + hv.w*bfbits2f(wv[3]);
            }
            a0 += acc4[0]; a1 += acc4[1]; a2 += acc4[2]; a3 += acc4[3];
        }
        logit = (a0 + a1) + (a2 + a3);
    }
    float mx = logit;
#pragma unroll
    for (int off=32; off; off>>=1) mx = fmaxf(mx, __shfl_xor(mx, off));
    const float e = (lane < Lseq) ? __expf(logit - mx) : 0.0f;
    float se = e;
#pragma unroll
    for (int off=32; off; off>>=1) se += __shfl_xor(se, off);
    const float myaw = e / se;

    float acc8[8] = {0.f,0.f,0.f,0.f,0.f,0.f,0.f,0.f};
    const bf16* eb = enc_out + (size_t)b*Lseq*Hd + lane*8;
    for (int l=0; l<Lseq; ++l){
        const float w = __shfl(myaw, l);
        const s16x8 ch = *reinterpret_cast<const s16x8*>(eb + (size_t)l*Hd);
#pragma unroll
        for (int q=0; q<8; ++q) acc8[q] += w * bfbits2f(ch[q]);
    }
    s16x8 ov;
#pragma unroll
    for (int q=0; q<8; ++q) ov[q] = f2bfbits(acc8[q]);
    *reinterpret_cast<s16x8*>(attnap + (size_t)b*Hd + lane*8) = ov;
}

// final pred (t = T-1)
__global__ __launch_bounds__(256) void pred_kernel(
    const int* __restrict__ flagp,
    const float* __restrict__ hf32,
    const bf16* __restrict__ outW, const bf16* __restrict__ outB,
    void* __restrict__ dout)
{
    const int f32out = *flagp;
    const int wave = threadIdx.x >> 6, lane = threadIdx.x & 63;
    const int b = blockIdx.x*4 + wave;
    float p0=0.f, p1=0.f, p2=0.f, p3=0.f;
    const float* hb = hf32 + (size_t)b*Hd;
    for (int k=lane; k<Hd; k+=64){
        const float hv = hb[k];
        p0 += hv*bf2f(outW[0*Hd+k]);
        p1 += hv*bf2f(outW[1*Hd+k]);
        p2 += hv*bf2f(outW[2*Hd+k]);
        p3 += hv*bf2f(outW[3*Hd+k]);
    }
#pragma unroll
    for (int off=32; off; off>>=1){
        p0 += __shfl_down(p0, off); p1 += __shfl_down(p1, off);
        p2 += __shfl_down(p2, off); p3 += __shfl_down(p3, off);
    }
    if (lane == 0){
        const size_t o = ((size_t)b*Tlen + (Tlen-1))*Din;
        const float r0 = p0 + bf2f(outB[0]), r1 = p1 + bf2f(outB[1]);
        const float r2 = p2 + bf2f(outB[2]), r3 = p3 + bf2f(outB[3]);
        if (f32out){
            float* dp = (float*)dout + o;
            dp[0]=r0; dp[1]=r1; dp[2]=r2; dp[3]=r3;
        } else {
            bf16* dp = (bf16*)dout + o;
            dp[0]=f2bf(r0); dp[1]=f2bf(r1); dp[2]=f2bf(r2); dp[3]=f2bf(r3);
        }
    }
}

extern "C" void kernel_launch(void* const* d_in, const int* in_sizes, int n_in,
                              void* d_out, int out_size, void* d_ws, size_t ws_size,
                              hipStream_t stream)
{
    char* ws = (char*)d_ws;
    bf16*  Abuf0   = (bf16*)(ws + OFF_ABUF0);
    bf16*  Abuf1   = (bf16*)(ws + OFF_ABUF1);
    float* cbuf    = (float*)(ws + OFF_CBUF);
    float* hf32    = (float*)(ws + OFF_HF32);
    bf16*  attnap  = (bf16*)(ws + OFF_ATTNAP);
    bf16*  xdec    = (bf16*)(ws + OFF_XDEC);
    int*   flag    = (int*)(ws + OFF_FLAG);
    bf16*  combWr  = (bf16*)(ws + OFF_COMBWR);
    bf16*  attnWr  = (bf16*)(ws + OFF_ATTNWR);
    bf16*  wc      = (bf16*)(ws + OFF_WCACHE);
    bf16*  enc_out = (bf16*)(ws + OFF_ENCOUT);

    const bf16 *c_input = wc+WC_INPUT, *c_eWih = wc+WC_EWIH, *c_eWhh = wc+WC_EWHH,
               *c_ebih = wc+WC_EBIH, *c_ebhh = wc+WC_EBHH, *c_aW = wc+WC_AW,
               *c_ab = wc+WC_AB, *c_cW = wc+WC_CW, *c_cb = wc+WC_CB,
               *c_dWih = wc+WC_DWIH, *c_dWhh = wc+WC_DWHH, *c_dbih = wc+WC_DBIH,
               *c_dbhh = wc+WC_DBHH, *c_oW = wc+WC_OW, *c_ob = wc+WC_OB;

    bf16* Abuf[2] = {Abuf0, Abuf1};

    probe_kernel<<<1, 256, 0, stream>>>((const unsigned int*)d_in[3], flag);

    Ptrs15 srcs;
    srcs.p[0]=d_in[0];  srcs.p[1]=d_in[2];  srcs.p[2]=d_in[3];  srcs.p[3]=d_in[4];
    srcs.p[4]=d_in[5];  srcs.p[5]=d_in[6];  srcs.p[6]=d_in[7];  srcs.p[7]=d_in[8];
    srcs.p[8]=d_in[9];  srcs.p[9]=d_in[10]; srcs.p[10]=d_in[11];srcs.p[11]=d_in[12];
    srcs.p[12]=d_in[13];srcs.p[13]=d_in[14];srcs.p[14]=d_in[15];
    convert_kernel<<<1024, 256, 0, stream>>>(srcs, flag, wc);

    setup_kernel<<<2048, 256, 0, stream>>>(Abuf0, Abuf1, cbuf, combWr, attnWr,
                                           c_cW, c_aW);

    // encoder: 50 fused LSTM steps, h double-buffered
    for (int t = 0; t < Lseq; ++t){
        gates_kernel<false, true, true><<<256, 512, 0, stream>>>(
            Abuf[t&1] + Hd, 1024,
            c_eWhh, c_eWhh, c_ebih, c_ebhh,
            c_eWih, c_input + (size_t)t*Din, Lseq*Din,
            cbuf,
            Abuf[(t+1)&1] + Hd,
            enc_out + (size_t)t*Hd, Lseq*Hd,
            hf32);
    }

    // decoder: 30 steps
    for (int t = 0; t < Tlen; ++t){
        const int p = t & 1;
        attn_kernel<<<256, 256, 0, stream>>>(
            t, flag, c_input, hf32, enc_out, c_aW, attnWr, c_ab, c_oW, c_ob,
            d_out, xdec, attnap);
        comb_kernel<<<256, 256, 0, stream>>>(
            attnap, combWr, c_cW, c_cb, xdec, Abuf[p]);
        gates_kernel<true, false, false><<<256, 512, 0, stream>>>(
            Abuf[p], 1024,
            c_dWih, c_dWhh, c_dbih, c_dbhh,
            nullptr, nullptr, 0,
            cbuf,
            Abuf[(t+1)&1] + Hd,
            nullptr, 0,
            hf32);
    }

    pred_kernel<<<256, 256, 0, stream>>>(flag, hf32, c_oW, c_ob, d_out);
}